// Round 7
// baseline (250.714 us; speedup 1.0000x reference)
//
#include <hip/hip_runtime.h>
#include <math.h>

#define N_IMG 8
#define N_ANCH 250000
#define PRE_K 2000
#define POST_K 1000
#define SORT_N 2048
#define CAND_CAP 8192  // >= G + boundary-bin count (expected ~5.7K, ~39 sigma margin)
#define NMS_WORDS 32   // ceil(2000/64)
#define NCHUNK 32      // ceil(2000/64) row-chunks of 64
#define CNT_STRIDE 64  // uints per image: 256B -> private cacheline per image

#define IMG_W_M1 1332.0f
#define IMG_H_M1 799.0f
#define DCLIP 4.135166556742356f
#define NMS_T 0.7f

__device__ __forceinline__ float rn_add(float a, float b){ return __fadd_rn(a,b); }
__device__ __forceinline__ float rn_sub(float a, float b){ return __fsub_rn(a,b); }
__device__ __forceinline__ float rn_mul(float a, float b){ return __fmul_rn(a,b); }
__device__ __forceinline__ float rn_div(float a, float b){ return __fdiv_rn(a,b); }

// monotonic float->uint mapping (order-preserving, larger float -> larger uint)
__device__ __forceinline__ unsigned int mono_of(float f){
  unsigned int u = __float_as_uint(f);
  return u ^ ((u >> 31) ? 0xFFFFFFFFu : 0x80000000u);
}

__device__ __forceinline__ unsigned long long shfl_u64(unsigned long long v, int lane){
  int lo = __shfl((int)(unsigned int)(v & 0xFFFFFFFFull), lane, 64);
  int hi = __shfl((int)(unsigned int)(v >> 32), lane, 64);
  return ((unsigned long long)(unsigned int)hi << 32) | (unsigned long long)(unsigned int)lo;
}

// async global->LDS DMA, 16B per lane (wave-uniform LDS base + lane*16)
__device__ __forceinline__ void gload_lds16(const unsigned long long* g, unsigned long long* l){
  __builtin_amdgcn_global_load_lds(
      (const __attribute__((address_space(1))) unsigned int*)g,
      (__attribute__((address_space(3))) unsigned int*)l, 16, 0, 0);
}

// exact-op-order IoU > 0.7 test (mirrors reference float32 op sequence)
__device__ __forceinline__ bool iou_gt(float x1,float y1,float x2,float y2,float a1,
                                       float X1,float Y1,float X2,float Y2,float a2){
  float ltx = fmaxf(x1, X1), lty = fmaxf(y1, Y1);
  float rbx = fminf(x2, X2), rby = fminf(y2, Y2);
  float wx = fmaxf(rn_add(rn_sub(rbx, ltx), 1.0f), 0.0f);
  float wy = fmaxf(rn_add(rn_sub(rby, lty), 1.0f), 0.0f);
  float inter = rn_mul(wx, wy);
  float iou = rn_div(inter, rn_sub(rn_add(a1, a2), inter));
  return iou > NMS_T;
}

// ---------------- init: zero hist + cnt ----------------
__global__ void k_init(unsigned int* hist, unsigned int* cnt){
  int t = blockIdx.x * blockDim.x + threadIdx.x;
  for (int i = t; i < N_IMG * 2048; i += gridDim.x * blockDim.x) hist[i] = 0;
  if (t < N_IMG * CNT_STRIDE) cnt[t] = 0;
}

// ---------------- single coarse histogram (top 11 bits), float4 loads ----------------
__global__ void k_hist(const float* __restrict__ obj, unsigned int* __restrict__ hist){
  __shared__ unsigned int lh[2048];
  int img = blockIdx.y;
  for (int i = threadIdx.x; i < 2048; i += blockDim.x) lh[i] = 0;
  __syncthreads();
  const float4* o4 = (const float4*)(obj + (size_t)img * N_ANCH);
  int stride = gridDim.x * blockDim.x;
  for (int i = blockIdx.x * blockDim.x + threadIdx.x; i < N_ANCH/4; i += stride){
    float4 v = o4[i];
    atomicAdd(&lh[mono_of(v.x) >> 21], 1u);
    atomicAdd(&lh[mono_of(v.y) >> 21], 1u);
    atomicAdd(&lh[mono_of(v.z) >> 21], 1u);
    atomicAdd(&lh[mono_of(v.w) >> 21], 1u);
  }
  __syncthreads();
  for (int i = threadIdx.x; i < 2048; i += blockDim.x)
    if (lh[i]) atomicAdd(&hist[img*2048 + i], lh[i]);
}

// ---------------- find boundary bin (few-iteration serial scan) ----------------
__global__ void k_scan(const unsigned int* __restrict__ hist, unsigned int* state){
  int img = blockIdx.x;
  if (threadIdx.x == 0){
    const unsigned int* h = hist + img * 2048;
    unsigned int cum = 0; int d;
    for (d = 2047; d >= 0; --d){ cum += h[d]; if (cum >= PRE_K) break; }
    state[img] = (unsigned int)d;
  }
}

// ---------------- collect candidates: top-11 bits >= boundary bin ----------------
// wave-aggregated atomics (round-4 lesson: per-thread same-line atomics
// serialize the dispatch); slot order arbitrary, later select+sort fixes order.
__global__ void k_cand(const float* __restrict__ obj, const unsigned int* __restrict__ state,
                       unsigned int* cnt, unsigned long long* __restrict__ cand){
  int img = blockIdx.y;
  unsigned int bin = state[img];
  const float4* o4 = (const float4*)(obj + (size_t)img * N_ANCH);
  int stride = gridDim.x * blockDim.x;
  int lane = threadIdx.x & 63;
  unsigned long long below = (lane == 0) ? 0ull : ((~0ull) >> (64 - lane));
  for (int i = blockIdx.x * blockDim.x + threadIdx.x; i < N_ANCH/4; i += stride){
    float4 v = o4[i];
    #pragma unroll
    for (int s = 0; s < 4; ++s){
      float f = (s==0) ? v.x : (s==1) ? v.y : (s==2) ? v.z : v.w;
      unsigned int key = mono_of(f);
      bool hit = (key >> 21) >= bin;
      unsigned long long b = __ballot(hit);
      if (b){
        int leader = (int)(__ffsll((long long)b) - 1);
        unsigned int base = 0;
        if (lane == leader) base = atomicAdd(&cnt[img*CNT_STRIDE], (unsigned int)__popcll(b));
        base = (unsigned int)__shfl((int)base, leader, 64);
        if (hit){
          unsigned int slot = base + (unsigned int)__popcll(b & below);
          if (slot < CAND_CAP)
            cand[(size_t)img*CAND_CAP + slot] =
              ((unsigned long long)key << 32) | (unsigned long long)(~(unsigned int)(i*4 + s));
        }
      }
    }
  }
}

// ---------------- per-image: exact radix select + tie rule + sort + decode ----------------
__global__ void __launch_bounds__(1024) k_selsort(
    const unsigned long long* __restrict__ cand, const unsigned int* __restrict__ cnt,
    const float* __restrict__ anchors, const float* __restrict__ deltas,
    float* __restrict__ boxes, float* __restrict__ scores,
    float* __restrict__ areas, unsigned int* __restrict__ valid){
  __shared__ unsigned long long sel_l[SORT_N];  // 16 KB
  __shared__ unsigned int bins[2048];           // 8 KB
  __shared__ unsigned int scal[4];              // rem, bin, cgt, ceq
  int img = blockIdx.x, tid = threadIdx.x;
  unsigned int n = cnt[img*CNT_STRIDE]; if (n > CAND_CAP) n = CAND_CAP;
  const unsigned long long* cd = cand + (size_t)img*CAND_CAP;

  unsigned int rem = PRE_K, prefix = 0;
  #pragma unroll
  for (int p = 0; p < 3; ++p){
    int shift  = (p==0) ? 21 : (p==1) ? 10 : 0;
    int mshift = (p==0) ? 32 : (p==1) ? 21 : 10;
    unsigned int bmask = (p==2) ? 1023u : 2047u;
    bins[tid] = 0; bins[tid+1024] = 0;
    __syncthreads();
    for (unsigned int i = tid; i < n; i += 1024){
      unsigned int k32 = (unsigned int)(cd[i] >> 32);
      bool m = (mshift >= 32) || ((k32 >> mshift) == (prefix >> mshift));
      if (m) atomicAdd(&bins[(k32 >> shift) & bmask], 1u);
    }
    __syncthreads();
    // parallel suffix-sum over 2048 bins (Hillis-Steele)
    for (int off = 1; off < 2048; off <<= 1){
      unsigned int a0 = bins[tid]      + ((tid+off      < 2048) ? bins[tid+off]      : 0u);
      unsigned int a1 = bins[tid+1024] + ((tid+1024+off < 2048) ? bins[tid+1024+off] : 0u);
      __syncthreads();
      bins[tid] = a0; bins[tid+1024] = a1;
      __syncthreads();
    }
    // unique d with S[d] >= rem > S[d+1]
    #pragma unroll
    for (int h = 0; h < 2; ++h){
      int d = tid + h*1024;
      unsigned int Sd  = bins[d];
      unsigned int Sd1 = (d < 2047) ? bins[d+1] : 0u;
      if (Sd >= rem && Sd1 < rem){ scal[0] = rem - Sd1; scal[1] = (unsigned int)d; }
    }
    __syncthreads();
    rem = scal[0]; prefix |= scal[1] << shift;
    __syncthreads();
  }
  unsigned int T = prefix;
  unsigned int G = PRE_K - rem;   // # strictly greater than T; rem ties needed
  if (tid == 0){ scal[2] = 0; scal[3] = 0; }
  __syncthreads();
  for (unsigned int i = tid; i < n; i += 1024){
    unsigned long long pk = cd[i];
    unsigned int k32 = (unsigned int)(pk >> 32);
    if (k32 > T){
      unsigned int s = atomicAdd(&scal[2], 1u);   // s < G <= 1999
      sel_l[s] = pk;
    } else if (k32 == T){
      unsigned int e = atomicAdd(&scal[3], 1u);
      if (G + e < SORT_N) sel_l[G + e] = pk;      // ties; first rem after sort = smallest idx
    }
  }
  __syncthreads();
  unsigned int ceq = scal[3];
  unsigned int tcap = SORT_N - G;
  unsigned int filled = G + ((ceq < tcap) ? ceq : tcap);
  for (unsigned int i = filled + tid; i < SORT_N; i += 1024) sel_l[i] = 0ull;
  __syncthreads();
  // bitonic sort 2048 descending: (key desc, idx asc) via ~idx packing
  for (int k = 2; k <= SORT_N; k <<= 1){
    for (int j = k >> 1; j > 0; j >>= 1){
      for (int i = tid; i < SORT_N; i += 1024){
        int ixj = i ^ j;
        if (ixj > i){
          bool up = ((i & k) == 0);
          unsigned long long x = sel_l[i], y = sel_l[ixj];
          if ((x < y) == up){ sel_l[i] = y; sel_l[ixj] = x; }
        }
      }
      __syncthreads();
    }
  }
  // decode + clip the exact top-2000 (score rebuilt bit-exactly from key)
  for (int k = tid; k < PRE_K; k += 1024){
    unsigned long long pk = sel_l[k];
    unsigned int key = (unsigned int)(pk >> 32);
    unsigned int idx = ~(unsigned int)(pk & 0xFFFFFFFFull);
    unsigned int ub = (key & 0x80000000u) ? (key ^ 0x80000000u) : (key ^ 0xFFFFFFFFu);
    float sc = __uint_as_float(ub);
    float4 a = ((const float4*)anchors)[idx];
    float4 d = ((const float4*)deltas)[(size_t)img*N_ANCH + idx];
    float w  = rn_add(rn_sub(a.z, a.x), 1.0f);
    float h  = rn_add(rn_sub(a.w, a.y), 1.0f);
    float cx = rn_add(a.x, rn_mul(0.5f, w));
    float cy = rn_add(a.y, rn_mul(0.5f, h));
    float dw = fminf(d.z, DCLIP);
    float dh = fminf(d.w, DCLIP);
    float pcx = rn_add(rn_mul(d.x, w), cx);
    float pcy = rn_add(rn_mul(d.y, h), cy);
    float pw = rn_mul((float)exp((double)dw), w);   // correctly-rounded f32 exp
    float ph = rn_mul((float)exp((double)dh), h);
    float x1 = rn_sub(pcx, rn_mul(0.5f, pw));
    float y1 = rn_sub(pcy, rn_mul(0.5f, ph));
    float x2 = rn_sub(rn_add(pcx, rn_mul(0.5f, pw)), 1.0f);
    float y2 = rn_sub(rn_add(pcy, rn_mul(0.5f, ph)), 1.0f);
    x1 = fminf(fmaxf(x1, 0.0f), IMG_W_M1);
    x2 = fminf(fmaxf(x2, 0.0f), IMG_W_M1);
    y1 = fminf(fmaxf(y1, 0.0f), IMG_H_M1);
    y2 = fminf(fmaxf(y2, 0.0f), IMG_H_M1);
    float bw = rn_add(rn_sub(x2, x1), 1.0f);
    float bh = rn_add(rn_sub(y2, y1), 1.0f);
    ((float4*)boxes)[(size_t)img*PRE_K + k] = make_float4(x1, y1, x2, y2);
    scores[img*PRE_K + k] = sc;
    areas[img*PRE_K + k]  = rn_mul(bw, bh);
    valid[img*PRE_K + k]  = (bw >= 0.0f && bh >= 0.0f) ? 1u : 0u;
  }
}

// ---------------- NMS suppression bitmask (upper triangle) ----------------
__global__ void k_mask(const float* __restrict__ boxes, const float* __restrict__ areas,
                       unsigned long long* __restrict__ mask){
  int jblk = blockIdx.x, iblk = blockIdx.y, img = blockIdx.z;
  if (jblk < iblk) return;
  __shared__ float4 jb[64];
  __shared__ float  ja[64];
  int tj = jblk*64 + threadIdx.x;
  if (tj < PRE_K){
    jb[threadIdx.x] = ((const float4*)boxes)[(size_t)img*PRE_K + tj];
    ja[threadIdx.x] = areas[img*PRE_K + tj];
  }
  __syncthreads();
  int i = iblk*64 + threadIdx.x;
  if (i >= PRE_K) return;
  float4 bi = ((const float4*)boxes)[(size_t)img*PRE_K + i];
  float ai = areas[img*PRE_K + i];
  unsigned long long bits = 0;
  int jmax = min(64, PRE_K - jblk*64);
  for (int b = 0; b < jmax; ++b){
    int j = jblk*64 + b;
    if (j <= i) continue;
    float4 bj = jb[b];
    if (iou_gt(bi.x,bi.y,bi.z,bi.w,ai, bj.x,bj.y,bj.z,bj.w,ja[b])) bits |= 1ull << b;
  }
  mask[((size_t)img*PRE_K + i)*NMS_WORDS + jblk] = bits;
}

// ---------------- pipelined greedy reduce + output pack ----------------
// Round-6 profile: 86 us, 27.8 GB/s, VALUBusy 0.46% -> exposed load latency
// (global->reg->LDS staging stalled each thread on its own vmcnt before
// ds_write + barrier). Fix: __builtin_amdgcn_global_load_lds direct-to-LDS
// DMA; the only wait left is the barrier's vmcnt drain, overlapped with the
// consumer wave's ~1000-cycle chunk reduce. Last-chunk OOB tail: clamp the
// GLOBAL source (garbage content is masked: rows >= 2000 are pre-removed in
// remv, so their dg/rw words are ANDed with 0); LDS dest keeps its slot.
__global__ void __launch_bounds__(1024) k_nms_out(const unsigned long long* __restrict__ mask,
                          const unsigned int* __restrict__ valid,
                          const float* __restrict__ boxes, const float* __restrict__ scores,
                          float* __restrict__ out){
  __shared__ unsigned long long lbuf[2][64 * NMS_WORDS];  // 2 x 16 KB
  __shared__ unsigned long long keepw[NMS_WORDS];
  __shared__ unsigned int kpre[NMS_WORDS + 1];
  int img = blockIdx.x;
  int tid = threadIdx.x;
  const unsigned long long* mrow = mask + (size_t)img * PRE_K * NMS_WORDS;
  const int TOT_U64 = PRE_K * NMS_WORDS;  // 64000

  unsigned long long remv = 0;
  if (tid < NMS_WORDS){
    for (int b = 0; b < 64; ++b){
      int i = tid*64 + b;
      bool ok = (i < PRE_K) && (valid[img*PRE_K + i] != 0u);
      if (!ok) remv |= 1ull << b;
    }
  }

  int wv = tid >> 6;     // wave id 0..15; waves 1..8 are loaders
  int lane = tid & 63;
  bool loader = (wv >= 1 && wv <= 8);

  // stage chunk cc into lbuf[cc&1] via direct-to-LDS DMA (16 x 1KB wave-calls)
  #define STAGE_CHUNK(cc) do{                                            \
    int _base = (cc) * 2048;                                             \
    _Pragma("unroll")                                                    \
    for (int _j = 0; _j < 2; ++_j){                                      \
      int _rel = ((wv-1)*2 + _j) * 128 + lane*2;                         \
      int _idx = _base + _rel;                                           \
      if (_idx > TOT_U64 - 2) _idx = TOT_U64 - 2;                        \
      gload_lds16(mrow + _idx, &lbuf[(cc) & 1][_rel]);                   \
    }                                                                    \
  } while(0)

  if (loader) STAGE_CHUNK(0);
  __syncthreads();

  for (int c = 0; c < NCHUNK; ++c){
    if (loader && (c + 1) < NCHUNK) STAGE_CHUNK(c + 1);
    // consumer wave: fused resolve+apply over the 64 rows of chunk c
    if (tid < 64){
      const unsigned long long* B = &lbuf[c & 1][0];
      int w = tid;
      int wm = w & (NMS_WORDS - 1);
      unsigned long long k = ~shfl_u64(remv, c);
      unsigned long long acc = 0;
      for (int s = 0; s < 64; s += 8){
        const unsigned long long* Br = B + (size_t)s * NMS_WORDS;
        unsigned long long dg0 = Br[0*NMS_WORDS + c], rw0 = Br[0*NMS_WORDS + wm];
        unsigned long long dg1 = Br[1*NMS_WORDS + c], rw1 = Br[1*NMS_WORDS + wm];
        unsigned long long dg2 = Br[2*NMS_WORDS + c], rw2 = Br[2*NMS_WORDS + wm];
        unsigned long long dg3 = Br[3*NMS_WORDS + c], rw3 = Br[3*NMS_WORDS + wm];
        unsigned long long dg4 = Br[4*NMS_WORDS + c], rw4 = Br[4*NMS_WORDS + wm];
        unsigned long long dg5 = Br[5*NMS_WORDS + c], rw5 = Br[5*NMS_WORDS + wm];
        unsigned long long dg6 = Br[6*NMS_WORDS + c], rw6 = Br[6*NMS_WORDS + wm];
        unsigned long long dg7 = Br[7*NMS_WORDS + c], rw7 = Br[7*NMS_WORDS + wm];
        unsigned long long m;
        m = ((k >> (s+0)) & 1ull) ? ~0ull : 0ull; k &= ~(dg0 & m); acc |= rw0 & m;
        m = ((k >> (s+1)) & 1ull) ? ~0ull : 0ull; k &= ~(dg1 & m); acc |= rw1 & m;
        m = ((k >> (s+2)) & 1ull) ? ~0ull : 0ull; k &= ~(dg2 & m); acc |= rw2 & m;
        m = ((k >> (s+3)) & 1ull) ? ~0ull : 0ull; k &= ~(dg3 & m); acc |= rw3 & m;
        m = ((k >> (s+4)) & 1ull) ? ~0ull : 0ull; k &= ~(dg4 & m); acc |= rw4 & m;
        m = ((k >> (s+5)) & 1ull) ? ~0ull : 0ull; k &= ~(dg5 & m); acc |= rw5 & m;
        m = ((k >> (s+6)) & 1ull) ? ~0ull : 0ull; k &= ~(dg6 & m); acc |= rw6 & m;
        m = ((k >> (s+7)) & 1ull) ? ~0ull : 0ull; k &= ~(dg7 & m); acc |= rw7 & m;
      }
      if (w == c)                      remv = ~k;
      else if (w > c && w < NMS_WORDS) remv |= acc;
    }
    __syncthreads();
  }
  #undef STAGE_CHUNK

  if (tid < NMS_WORDS) keepw[tid] = ~remv;
  __syncthreads();
  if (tid == 0){
    unsigned int s = 0;
    for (int w = 0; w < NMS_WORDS; ++w){ kpre[w] = s; s += __popcll(keepw[w]); }
    kpre[NMS_WORDS] = s;
  }
  __syncthreads();
  unsigned int nkept = kpre[NMS_WORDS];
  for (int i = tid; i < PRE_K; i += blockDim.x){
    int w = i >> 6, b = i & 63;
    unsigned long long kw = keepw[w];
    bool kept = (kw >> b) & 1ull;
    unsigned long long below = (b == 0) ? 0ull : (kw & ((~0ull) >> (64 - b)));
    unsigned int rank = kpre[w] + (unsigned int)__popcll(below);
    unsigned int pos = kept ? rank : (nkept + (unsigned int)i - rank);
    if (pos < POST_K){
      float4 bx = ((const float4*)boxes)[(size_t)img*PRE_K + i];
      float sc = kept ? scores[img*PRE_K + i] : -1e9f;
      float* o = out + ((size_t)img*POST_K + pos) * 5;
      o[0] = bx.x; o[1] = bx.y; o[2] = bx.z; o[3] = bx.w; o[4] = sc;
    }
  }
}

extern "C" void kernel_launch(void* const* d_in, const int* in_sizes, int n_in,
                              void* d_out, int out_size, void* d_ws, size_t ws_size,
                              hipStream_t stream) {
  const float* anchors    = (const float*)d_in[0];
  const float* objectness = (const float*)d_in[1];
  const float* deltas     = (const float*)d_in[2];
  float* out = (float*)d_out;
  char* ws = (char*)d_ws;

  unsigned int* hist       = (unsigned int*)(ws + 0);        // 65536
  unsigned int* state      = (unsigned int*)(ws + 65536);    // 32
  unsigned int* cnt        = (unsigned int*)(ws + 65600);    // 2048 (256B/img)
  float* boxes             = (float*)(ws + 67648);           // 256000 (16B aligned)
  float* scores            = (float*)(ws + 323648);          // 64000
  float* areas             = (float*)(ws + 387648);          // 64000
  unsigned int* valid      = (unsigned int*)(ws + 451648);   // 64000
  unsigned long long* mask = (unsigned long long*)(ws + 515648); // 4096000
  // candidate buffer overlays mask region: fully consumed by k_selsort BEFORE
  // k_mask writes mask (in-order stream). 8*8192*8 = 512 KB <= 4 MB.
  unsigned long long* cand = (unsigned long long*)(ws + 515648);

  hipLaunchKernelGGL(k_init, dim3(32), dim3(256), 0, stream, hist, cnt);
  hipLaunchKernelGGL(k_hist, dim3(8, N_IMG), dim3(256), 0, stream, objectness, hist);
  hipLaunchKernelGGL(k_scan, dim3(N_IMG), dim3(64), 0, stream, hist, state);
  hipLaunchKernelGGL(k_cand, dim3(32, N_IMG), dim3(256), 0, stream,
                     objectness, state, cnt, cand);
  hipLaunchKernelGGL(k_selsort, dim3(N_IMG), dim3(1024), 0, stream,
                     cand, cnt, anchors, deltas, boxes, scores, areas, valid);
  hipLaunchKernelGGL(k_mask, dim3(NMS_WORDS, NMS_WORDS, N_IMG), dim3(64), 0, stream,
                     boxes, areas, mask);
  hipLaunchKernelGGL(k_nms_out, dim3(N_IMG), dim3(1024), 0, stream,
                     mask, valid, boxes, scores, out);
}

// Round 8
// 211.884 us; speedup vs baseline: 1.1833x; 1.1833x over previous
//
#include <hip/hip_runtime.h>
#include <math.h>

#define N_IMG 8
#define N_ANCH 250000
#define PRE_K 2000
#define POST_K 1000
#define SORT_N 2048
#define CAND_CAP 8192  // >= G + boundary-bin count (expected ~5.7K, ~39 sigma margin)
#define NMS_WORDS 32   // ceil(2000/64)
#define NCHUNK 32      // row-chunks of 64 (rows padded to 2048)
#define MT_ROWS 2048   // transposed mask rows per word (padded)
#define CNT_STRIDE 64  // uints per image: 256B -> private cacheline per image

#define IMG_W_M1 1332.0f
#define IMG_H_M1 799.0f
#define DCLIP 4.135166556742356f
#define NMS_T 0.7f

__device__ __forceinline__ float rn_add(float a, float b){ return __fadd_rn(a,b); }
__device__ __forceinline__ float rn_sub(float a, float b){ return __fsub_rn(a,b); }
__device__ __forceinline__ float rn_mul(float a, float b){ return __fmul_rn(a,b); }
__device__ __forceinline__ float rn_div(float a, float b){ return __fdiv_rn(a,b); }

// monotonic float->uint mapping (order-preserving, larger float -> larger uint)
__device__ __forceinline__ unsigned int mono_of(float f){
  unsigned int u = __float_as_uint(f);
  return u ^ ((u >> 31) ? 0xFFFFFFFFu : 0x80000000u);
}

__device__ __forceinline__ unsigned long long shflx_u64(unsigned long long v, int m){
  int lo = __shfl_xor((int)(unsigned int)(v & 0xFFFFFFFFull), m, 64);
  int hi = __shfl_xor((int)(unsigned int)(v >> 32), m, 64);
  return ((unsigned long long)(unsigned int)hi << 32) | (unsigned long long)(unsigned int)lo;
}

// v_readlane (no LDS traffic) -- lane may be an immediate or uniform value
__device__ __forceinline__ unsigned long long readlane64(unsigned long long v, int l){
  unsigned int lo = __builtin_amdgcn_readlane((unsigned int)(v & 0xFFFFFFFFull), l);
  unsigned int hi = __builtin_amdgcn_readlane((unsigned int)(v >> 32), l);
  return ((unsigned long long)hi << 32) | (unsigned long long)lo;
}

// exact-op-order IoU > 0.7 test (mirrors reference float32 op sequence)
__device__ __forceinline__ bool iou_gt(float x1,float y1,float x2,float y2,float a1,
                                       float X1,float Y1,float X2,float Y2,float a2){
  float ltx = fmaxf(x1, X1), lty = fmaxf(y1, Y1);
  float rbx = fminf(x2, X2), rby = fminf(y2, Y2);
  float wx = fmaxf(rn_add(rn_sub(rbx, ltx), 1.0f), 0.0f);
  float wy = fmaxf(rn_add(rn_sub(rby, lty), 1.0f), 0.0f);
  float inter = rn_mul(wx, wy);
  float iou = rn_div(inter, rn_sub(rn_add(a1, a2), inter));
  return iou > NMS_T;
}

// ---------------- init: zero hist + cnt ----------------
__global__ void k_init(unsigned int* hist, unsigned int* cnt){
  int t = blockIdx.x * blockDim.x + threadIdx.x;
  for (int i = t; i < N_IMG * 2048; i += gridDim.x * blockDim.x) hist[i] = 0;
  if (t < N_IMG * CNT_STRIDE) cnt[t] = 0;
}

// ---------------- single coarse histogram (top 11 bits), float4 loads ----------------
__global__ void k_hist(const float* __restrict__ obj, unsigned int* __restrict__ hist){
  __shared__ unsigned int lh[2048];
  int img = blockIdx.y;
  for (int i = threadIdx.x; i < 2048; i += blockDim.x) lh[i] = 0;
  __syncthreads();
  const float4* o4 = (const float4*)(obj + (size_t)img * N_ANCH);
  int stride = gridDim.x * blockDim.x;
  for (int i = blockIdx.x * blockDim.x + threadIdx.x; i < N_ANCH/4; i += stride){
    float4 v = o4[i];
    atomicAdd(&lh[mono_of(v.x) >> 21], 1u);
    atomicAdd(&lh[mono_of(v.y) >> 21], 1u);
    atomicAdd(&lh[mono_of(v.z) >> 21], 1u);
    atomicAdd(&lh[mono_of(v.w) >> 21], 1u);
  }
  __syncthreads();
  for (int i = threadIdx.x; i < 2048; i += blockDim.x)
    if (lh[i]) atomicAdd(&hist[img*2048 + i], lh[i]);
}

// ---------------- find boundary bin (few-iteration serial scan) ----------------
__global__ void k_scan(const unsigned int* __restrict__ hist, unsigned int* state){
  int img = blockIdx.x;
  if (threadIdx.x == 0){
    const unsigned int* h = hist + img * 2048;
    unsigned int cum = 0; int d;
    for (d = 2047; d >= 0; --d){ cum += h[d]; if (cum >= PRE_K) break; }
    state[img] = (unsigned int)d;
  }
}

// ---------------- collect candidates: top-11 bits >= boundary bin ----------------
__global__ void k_cand(const float* __restrict__ obj, const unsigned int* __restrict__ state,
                       unsigned int* cnt, unsigned long long* __restrict__ cand){
  int img = blockIdx.y;
  unsigned int bin = state[img];
  const float4* o4 = (const float4*)(obj + (size_t)img * N_ANCH);
  int stride = gridDim.x * blockDim.x;
  int lane = threadIdx.x & 63;
  unsigned long long below = (lane == 0) ? 0ull : ((~0ull) >> (64 - lane));
  for (int i = blockIdx.x * blockDim.x + threadIdx.x; i < N_ANCH/4; i += stride){
    float4 v = o4[i];
    #pragma unroll
    for (int s = 0; s < 4; ++s){
      float f = (s==0) ? v.x : (s==1) ? v.y : (s==2) ? v.z : v.w;
      unsigned int key = mono_of(f);
      bool hit = (key >> 21) >= bin;
      unsigned long long b = __ballot(hit);
      if (b){
        int leader = (int)(__ffsll((long long)b) - 1);
        unsigned int base = 0;
        if (lane == leader) base = atomicAdd(&cnt[img*CNT_STRIDE], (unsigned int)__popcll(b));
        base = (unsigned int)__shfl((int)base, leader, 64);
        if (hit){
          unsigned int slot = base + (unsigned int)__popcll(b & below);
          if (slot < CAND_CAP)
            cand[(size_t)img*CAND_CAP + slot] =
              ((unsigned long long)key << 32) | (unsigned long long)(~(unsigned int)(i*4 + s));
        }
      }
    }
  }
}

// ---------------- per-image: exact radix select + tie rule + sort + decode ----------------
__global__ void __launch_bounds__(1024) k_selsort(
    const unsigned long long* __restrict__ cand, const unsigned int* __restrict__ cnt,
    const float* __restrict__ anchors, const float* __restrict__ deltas,
    float* __restrict__ boxes, float* __restrict__ scores,
    float* __restrict__ areas, unsigned int* __restrict__ valid){
  __shared__ unsigned long long sel_l[SORT_N];  // 16 KB
  __shared__ unsigned int bins[2048];           // 8 KB
  __shared__ unsigned int scal[4];              // rem, bin, cgt, ceq
  int img = blockIdx.x, tid = threadIdx.x;
  unsigned int n = cnt[img*CNT_STRIDE]; if (n > CAND_CAP) n = CAND_CAP;
  const unsigned long long* cd = cand + (size_t)img*CAND_CAP;

  unsigned int rem = PRE_K, prefix = 0;
  #pragma unroll
  for (int p = 0; p < 3; ++p){
    int shift  = (p==0) ? 21 : (p==1) ? 10 : 0;
    int mshift = (p==0) ? 32 : (p==1) ? 21 : 10;
    unsigned int bmask = (p==2) ? 1023u : 2047u;
    bins[tid] = 0; bins[tid+1024] = 0;
    __syncthreads();
    for (unsigned int i = tid; i < n; i += 1024){
      unsigned int k32 = (unsigned int)(cd[i] >> 32);
      bool m = (mshift >= 32) || ((k32 >> mshift) == (prefix >> mshift));
      if (m) atomicAdd(&bins[(k32 >> shift) & bmask], 1u);
    }
    __syncthreads();
    // parallel suffix-sum over 2048 bins (Hillis-Steele)
    for (int off = 1; off < 2048; off <<= 1){
      unsigned int a0 = bins[tid]      + ((tid+off      < 2048) ? bins[tid+off]      : 0u);
      unsigned int a1 = bins[tid+1024] + ((tid+1024+off < 2048) ? bins[tid+1024+off] : 0u);
      __syncthreads();
      bins[tid] = a0; bins[tid+1024] = a1;
      __syncthreads();
    }
    // unique d with S[d] >= rem > S[d+1]
    #pragma unroll
    for (int h = 0; h < 2; ++h){
      int d = tid + h*1024;
      unsigned int Sd  = bins[d];
      unsigned int Sd1 = (d < 2047) ? bins[d+1] : 0u;
      if (Sd >= rem && Sd1 < rem){ scal[0] = rem - Sd1; scal[1] = (unsigned int)d; }
    }
    __syncthreads();
    rem = scal[0]; prefix |= scal[1] << shift;
    __syncthreads();
  }
  unsigned int T = prefix;
  unsigned int G = PRE_K - rem;   // # strictly greater than T; rem ties needed
  if (tid == 0){ scal[2] = 0; scal[3] = 0; }
  __syncthreads();
  for (unsigned int i = tid; i < n; i += 1024){
    unsigned long long pk = cd[i];
    unsigned int k32 = (unsigned int)(pk >> 32);
    if (k32 > T){
      unsigned int s = atomicAdd(&scal[2], 1u);   // s < G <= 1999
      sel_l[s] = pk;
    } else if (k32 == T){
      unsigned int e = atomicAdd(&scal[3], 1u);
      if (G + e < SORT_N) sel_l[G + e] = pk;      // ties; first rem after sort = smallest idx
    }
  }
  __syncthreads();
  unsigned int ceq = scal[3];
  unsigned int tcap = SORT_N - G;
  unsigned int filled = G + ((ceq < tcap) ? ceq : tcap);
  for (unsigned int i = filled + tid; i < SORT_N; i += 1024) sel_l[i] = 0ull;
  __syncthreads();
  // bitonic sort 2048 descending: (key desc, idx asc) via ~idx packing
  for (int k = 2; k <= SORT_N; k <<= 1){
    for (int j = k >> 1; j > 0; j >>= 1){
      for (int i = tid; i < SORT_N; i += 1024){
        int ixj = i ^ j;
        if (ixj > i){
          bool up = ((i & k) == 0);
          unsigned long long x = sel_l[i], y = sel_l[ixj];
          if ((x < y) == up){ sel_l[i] = y; sel_l[ixj] = x; }
        }
      }
      __syncthreads();
    }
  }
  // decode + clip the exact top-2000 (score rebuilt bit-exactly from key)
  for (int k = tid; k < PRE_K; k += 1024){
    unsigned long long pk = sel_l[k];
    unsigned int key = (unsigned int)(pk >> 32);
    unsigned int idx = ~(unsigned int)(pk & 0xFFFFFFFFull);
    unsigned int ub = (key & 0x80000000u) ? (key ^ 0x80000000u) : (key ^ 0xFFFFFFFFu);
    float sc = __uint_as_float(ub);
    float4 a = ((const float4*)anchors)[idx];
    float4 d = ((const float4*)deltas)[(size_t)img*N_ANCH + idx];
    float w  = rn_add(rn_sub(a.z, a.x), 1.0f);
    float h  = rn_add(rn_sub(a.w, a.y), 1.0f);
    float cx = rn_add(a.x, rn_mul(0.5f, w));
    float cy = rn_add(a.y, rn_mul(0.5f, h));
    float dw = fminf(d.z, DCLIP);
    float dh = fminf(d.w, DCLIP);
    float pcx = rn_add(rn_mul(d.x, w), cx);
    float pcy = rn_add(rn_mul(d.y, h), cy);
    float pw = rn_mul((float)exp((double)dw), w);   // correctly-rounded f32 exp
    float ph = rn_mul((float)exp((double)dh), h);
    float x1 = rn_sub(pcx, rn_mul(0.5f, pw));
    float y1 = rn_sub(pcy, rn_mul(0.5f, ph));
    float x2 = rn_sub(rn_add(pcx, rn_mul(0.5f, pw)), 1.0f);
    float y2 = rn_sub(rn_add(pcy, rn_mul(0.5f, ph)), 1.0f);
    x1 = fminf(fmaxf(x1, 0.0f), IMG_W_M1);
    x2 = fminf(fmaxf(x2, 0.0f), IMG_W_M1);
    y1 = fminf(fmaxf(y1, 0.0f), IMG_H_M1);
    y2 = fminf(fmaxf(y2, 0.0f), IMG_H_M1);
    float bw = rn_add(rn_sub(x2, x1), 1.0f);
    float bh = rn_add(rn_sub(y2, y1), 1.0f);
    ((float4*)boxes)[(size_t)img*PRE_K + k] = make_float4(x1, y1, x2, y2);
    scores[img*PRE_K + k] = sc;
    areas[img*PRE_K + k]  = rn_mul(bw, bh);
    valid[img*PRE_K + k]  = (bw >= 0.0f && bh >= 0.0f) ? 1u : 0u;
  }
}

// ---------------- NMS suppression bitmask, TRANSPOSED: mask_t[word][row] ----------------
// row-coalesced writes; rows [PRE_K, 2048) zeroed so downstream reads are safe.
__global__ void k_mask(const float* __restrict__ boxes, const float* __restrict__ areas,
                       unsigned long long* __restrict__ mask){
  int jblk = blockIdx.x, iblk = blockIdx.y, img = blockIdx.z;
  if (jblk < iblk) return;
  __shared__ float4 jb[64];
  __shared__ float  ja[64];
  int tj = jblk*64 + threadIdx.x;
  if (tj < PRE_K){
    jb[threadIdx.x] = ((const float4*)boxes)[(size_t)img*PRE_K + tj];
    ja[threadIdx.x] = areas[img*PRE_K + tj];
  }
  __syncthreads();
  int i = iblk*64 + threadIdx.x;
  unsigned long long bits = 0;
  if (i < PRE_K){
    float4 bi = ((const float4*)boxes)[(size_t)img*PRE_K + i];
    float ai = areas[img*PRE_K + i];
    int jmax = min(64, PRE_K - jblk*64);
    for (int b = 0; b < jmax; ++b){
      int j = jblk*64 + b;
      if (j <= i) continue;
      float4 bj = jb[b];
      if (iou_gt(bi.x,bi.y,bi.z,bi.w,ai, bj.x,bj.y,bj.z,bj.w,ja[b])) bits |= 1ull << b;
    }
  }
  mask[(size_t)img*(NMS_WORDS*MT_ROWS) + (size_t)jblk*MT_ROWS + i] = bits;
}

// ---------------- greedy NMS reduce: register-resident resolve + distributed apply ------
// Round-7 evidence: two different staging schemes gave identical 86 us ->
// bottleneck was the consumer's serial LDS-latency chain (VGPR=36 allocator
// split the read batches). New scheme has ZERO memory ops on the serial path:
//  - each wave preloads its 2 chunks' diagonal words into per-lane regs,
//  - resolve = 64-step unrolled v_readlane + scalar and-not chain (~400 cyc),
//  - apply distributed over all 16 waves, 1 coalesced global ulonglong2 per
//    thread per chunk (prefetched 1 chunk ahead), private reg accumulators,
//  - word partials reduced with 5 shfl_xor only when that chunk resolves,
//  - ONE barrier per chunk.
__global__ void __launch_bounds__(1024) k_nms_out(const unsigned long long* __restrict__ mask,
                          const unsigned int* __restrict__ valid,
                          const float* __restrict__ boxes, const float* __restrict__ scores,
                          float* __restrict__ out){
  __shared__ unsigned long long keepw[NMS_WORDS];
  __shared__ unsigned int kpre[NMS_WORDS + 1];
  int img = blockIdx.x;
  int tid = threadIdx.x;
  int wv = tid >> 6, lane = tid & 63;
  const unsigned long long* mt = mask + (size_t)img * (NMS_WORDS * MT_ROWS);

  // preload this wave's two diagonal words + valid ballots (chunks 2wv, 2wv+1)
  int cA = wv*2, cB = wv*2 + 1;
  unsigned long long dgA = mt[(size_t)cA*MT_ROWS + cA*64 + lane];
  unsigned long long dgB = mt[(size_t)cB*MT_ROWS + cB*64 + lane];
  int rA = cA*64 + lane, rB = cB*64 + lane;
  bool okA = (rA < PRE_K) && (valid[img*PRE_K + rA] != 0u);
  bool okB = (rB < PRE_K) && (valid[img*PRE_K + rB] != 0u);
  unsigned long long vA = __ballot(okA);
  unsigned long long vB = __ballot(okB);

  // apply mapping: thread -> (word w, row-pair r2); acc = private suppression partial
  int w  = wv*2 + (lane >> 5);
  int r2 = lane & 31;
  unsigned long long acc = 0;

  ulonglong2 cur; cur.x = 0; cur.y = 0;
  if (w > 0)
    cur = *(const ulonglong2*)(mt + (size_t)w*MT_ROWS + r2*2);

  for (int c = 0; c < NCHUNK; ++c){
    if (wv == (c >> 1)){
      // reduce word-c partials (held in one 32-lane half of this wave)
      unsigned long long part = acc;
      part |= shflx_u64(part, 1);
      part |= shflx_u64(part, 2);
      part |= shflx_u64(part, 4);
      part |= shflx_u64(part, 8);
      part |= shflx_u64(part, 16);
      unsigned long long sup = readlane64(part, (c & 1) * 32);
      unsigned long long k = ((c & 1) ? vB : vA) & ~sup;
      unsigned long long dg = (c & 1) ? dgB : dgA;
      // serial greedy within chunk: pure register/readlane chain, branchless
      #pragma unroll
      for (int b = 0; b < 64; ++b){
        unsigned long long dgb = readlane64(dg, b);
        unsigned long long m = ((k >> b) & 1ull) ? ~0ull : 0ull;
        k &= ~(m & dgb);   // dg strictly upper-triangular: only bits > b affected
      }
      if (lane == 0) keepw[c] = k;
    }
    __syncthreads();
    // prefetch next chunk's row-pair for this thread's word
    ulonglong2 nxt; nxt.x = 0; nxt.y = 0;
    if (c + 1 < NCHUNK && w > c + 1)
      nxt = *(const ulonglong2*)(mt + (size_t)w*MT_ROWS + (size_t)(c+1)*64 + r2*2);
    unsigned long long kb = keepw[c];
    if (w > c){
      unsigned long long m0 = ((kb >> (r2*2))   & 1ull) ? ~0ull : 0ull;
      unsigned long long m1 = ((kb >> (r2*2+1)) & 1ull) ? ~0ull : 0ull;
      acc |= (cur.x & m0) | (cur.y & m1);
    }
    cur = nxt;
  }

  // pack: keepw[] holds final keep words
  if (tid == 0){
    unsigned int s = 0;
    for (int ww = 0; ww < NMS_WORDS; ++ww){ kpre[ww] = s; s += __popcll(keepw[ww]); }
    kpre[NMS_WORDS] = s;
  }
  __syncthreads();
  unsigned int nkept = kpre[NMS_WORDS];
  for (int i = tid; i < PRE_K; i += blockDim.x){
    int ww = i >> 6, b = i & 63;
    unsigned long long kw = keepw[ww];
    bool kept = (kw >> b) & 1ull;
    unsigned long long below = (b == 0) ? 0ull : (kw & ((~0ull) >> (64 - b)));
    unsigned int rank = kpre[ww] + (unsigned int)__popcll(below);
    unsigned int pos = kept ? rank : (nkept + (unsigned int)i - rank);
    if (pos < POST_K){
      float4 bx = ((const float4*)boxes)[(size_t)img*PRE_K + i];
      float sc = kept ? scores[img*PRE_K + i] : -1e9f;
      float* o = out + ((size_t)img*POST_K + pos) * 5;
      o[0] = bx.x; o[1] = bx.y; o[2] = bx.z; o[3] = bx.w; o[4] = sc;
    }
  }
}

extern "C" void kernel_launch(void* const* d_in, const int* in_sizes, int n_in,
                              void* d_out, int out_size, void* d_ws, size_t ws_size,
                              hipStream_t stream) {
  const float* anchors    = (const float*)d_in[0];
  const float* objectness = (const float*)d_in[1];
  const float* deltas     = (const float*)d_in[2];
  float* out = (float*)d_out;
  char* ws = (char*)d_ws;

  unsigned int* hist       = (unsigned int*)(ws + 0);        // 65536
  unsigned int* state      = (unsigned int*)(ws + 65536);    // 32
  unsigned int* cnt        = (unsigned int*)(ws + 65600);    // 2048 (256B/img)
  float* boxes             = (float*)(ws + 67648);           // 256000 (16B aligned)
  float* scores            = (float*)(ws + 323648);          // 64000
  float* areas             = (float*)(ws + 387648);          // 64000
  unsigned int* valid      = (unsigned int*)(ws + 451648);   // 64000
  unsigned long long* mask = (unsigned long long*)(ws + 515648); // 4,194,304 (transposed, 2048 rows)
  // candidate buffer overlays mask region: fully consumed by k_selsort BEFORE
  // k_mask writes mask (in-order stream). 8*8192*8 = 512 KB <= 4 MB.
  unsigned long long* cand = (unsigned long long*)(ws + 515648);

  hipLaunchKernelGGL(k_init, dim3(32), dim3(256), 0, stream, hist, cnt);
  hipLaunchKernelGGL(k_hist, dim3(8, N_IMG), dim3(256), 0, stream, objectness, hist);
  hipLaunchKernelGGL(k_scan, dim3(N_IMG), dim3(64), 0, stream, hist, state);
  hipLaunchKernelGGL(k_cand, dim3(32, N_IMG), dim3(256), 0, stream,
                     objectness, state, cnt, cand);
  hipLaunchKernelGGL(k_selsort, dim3(N_IMG), dim3(1024), 0, stream,
                     cand, cnt, anchors, deltas, boxes, scores, areas, valid);
  hipLaunchKernelGGL(k_mask, dim3(NMS_WORDS, NMS_WORDS, N_IMG), dim3(64), 0, stream,
                     boxes, areas, mask);
  hipLaunchKernelGGL(k_nms_out, dim3(N_IMG), dim3(1024), 0, stream,
                     mask, valid, boxes, scores, out);
}

// Round 9
// 203.360 us; speedup vs baseline: 1.2329x; 1.0419x over previous
//
#include <hip/hip_runtime.h>
#include <math.h>

#define N_IMG 8
#define N_ANCH 250000
#define PRE_K 2000
#define POST_K 1000
#define SORT_N 2048
#define CAND_CAP 8192  // >= G + boundary-bin count (expected ~5.7K, ~39 sigma margin)
#define NMS_WORDS 32   // ceil(2000/64)
#define NPAIR 16       // pairs of 64-row chunks
#define MT_ROWS 2048   // transposed mask rows per word (padded)
#define CNT_STRIDE 64  // uints per image: 256B -> private cacheline per image

#define IMG_W_M1 1332.0f
#define IMG_H_M1 799.0f
#define DCLIP 4.135166556742356f
#define NMS_T 0.7f

__device__ __forceinline__ float rn_add(float a, float b){ return __fadd_rn(a,b); }
__device__ __forceinline__ float rn_sub(float a, float b){ return __fsub_rn(a,b); }
__device__ __forceinline__ float rn_mul(float a, float b){ return __fmul_rn(a,b); }
__device__ __forceinline__ float rn_div(float a, float b){ return __fdiv_rn(a,b); }

// monotonic float->uint mapping (order-preserving, larger float -> larger uint)
__device__ __forceinline__ unsigned int mono_of(float f){
  unsigned int u = __float_as_uint(f);
  return u ^ ((u >> 31) ? 0xFFFFFFFFu : 0x80000000u);
}

__device__ __forceinline__ unsigned long long shflx_u64(unsigned long long v, int m){
  int lo = __shfl_xor((int)(unsigned int)(v & 0xFFFFFFFFull), m, 64);
  int hi = __shfl_xor((int)(unsigned int)(v >> 32), m, 64);
  return ((unsigned long long)(unsigned int)hi << 32) | (unsigned long long)(unsigned int)lo;
}

// v_readlane (no LDS traffic) -- lane is an immediate or uniform value
__device__ __forceinline__ unsigned long long readlane64(unsigned long long v, int l){
  unsigned int lo = __builtin_amdgcn_readlane((unsigned int)(v & 0xFFFFFFFFull), l);
  unsigned int hi = __builtin_amdgcn_readlane((unsigned int)(v >> 32), l);
  return ((unsigned long long)hi << 32) | (unsigned long long)lo;
}

// exact-op-order IoU > 0.7 test (mirrors reference float32 op sequence)
__device__ __forceinline__ bool iou_gt(float x1,float y1,float x2,float y2,float a1,
                                       float X1,float Y1,float X2,float Y2,float a2){
  float ltx = fmaxf(x1, X1), lty = fmaxf(y1, Y1);
  float rbx = fminf(x2, X2), rby = fminf(y2, Y2);
  float wx = fmaxf(rn_add(rn_sub(rbx, ltx), 1.0f), 0.0f);
  float wy = fmaxf(rn_add(rn_sub(rby, lty), 1.0f), 0.0f);
  float inter = rn_mul(wx, wy);
  float iou = rn_div(inter, rn_sub(rn_add(a1, a2), inter));
  return iou > NMS_T;
}

// ---------------- init: zero hist + cnt ----------------
__global__ void k_init(unsigned int* hist, unsigned int* cnt){
  int t = blockIdx.x * blockDim.x + threadIdx.x;
  for (int i = t; i < N_IMG * 2048; i += gridDim.x * blockDim.x) hist[i] = 0;
  if (t < N_IMG * CNT_STRIDE) cnt[t] = 0;
}

// ---------------- single coarse histogram (top 11 bits), float4 loads ----------------
__global__ void k_hist(const float* __restrict__ obj, unsigned int* __restrict__ hist){
  __shared__ unsigned int lh[2048];
  int img = blockIdx.y;
  for (int i = threadIdx.x; i < 2048; i += blockDim.x) lh[i] = 0;
  __syncthreads();
  const float4* o4 = (const float4*)(obj + (size_t)img * N_ANCH);
  int stride = gridDim.x * blockDim.x;
  for (int i = blockIdx.x * blockDim.x + threadIdx.x; i < N_ANCH/4; i += stride){
    float4 v = o4[i];
    atomicAdd(&lh[mono_of(v.x) >> 21], 1u);
    atomicAdd(&lh[mono_of(v.y) >> 21], 1u);
    atomicAdd(&lh[mono_of(v.z) >> 21], 1u);
    atomicAdd(&lh[mono_of(v.w) >> 21], 1u);
  }
  __syncthreads();
  for (int i = threadIdx.x; i < 2048; i += blockDim.x)
    if (lh[i]) atomicAdd(&hist[img*2048 + i], lh[i]);
}

// ---------------- find boundary bin (few-iteration serial scan) ----------------
__global__ void k_scan(const unsigned int* __restrict__ hist, unsigned int* state){
  int img = blockIdx.x;
  if (threadIdx.x == 0){
    const unsigned int* h = hist + img * 2048;
    unsigned int cum = 0; int d;
    for (d = 2047; d >= 0; --d){ cum += h[d]; if (cum >= PRE_K) break; }
    state[img] = (unsigned int)d;
  }
}

// ---------------- collect candidates: top-11 bits >= boundary bin ----------------
__global__ void k_cand(const float* __restrict__ obj, const unsigned int* __restrict__ state,
                       unsigned int* cnt, unsigned long long* __restrict__ cand){
  int img = blockIdx.y;
  unsigned int bin = state[img];
  const float4* o4 = (const float4*)(obj + (size_t)img * N_ANCH);
  int stride = gridDim.x * blockDim.x;
  int lane = threadIdx.x & 63;
  unsigned long long below = (lane == 0) ? 0ull : ((~0ull) >> (64 - lane));
  for (int i = blockIdx.x * blockDim.x + threadIdx.x; i < N_ANCH/4; i += stride){
    float4 v = o4[i];
    #pragma unroll
    for (int s = 0; s < 4; ++s){
      float f = (s==0) ? v.x : (s==1) ? v.y : (s==2) ? v.z : v.w;
      unsigned int key = mono_of(f);
      bool hit = (key >> 21) >= bin;
      unsigned long long b = __ballot(hit);
      if (b){
        int leader = (int)(__ffsll((long long)b) - 1);
        unsigned int base = 0;
        if (lane == leader) base = atomicAdd(&cnt[img*CNT_STRIDE], (unsigned int)__popcll(b));
        base = (unsigned int)__shfl((int)base, leader, 64);
        if (hit){
          unsigned int slot = base + (unsigned int)__popcll(b & below);
          if (slot < CAND_CAP)
            cand[(size_t)img*CAND_CAP + slot] =
              ((unsigned long long)key << 32) | (unsigned long long)(~(unsigned int)(i*4 + s));
        }
      }
    }
  }
}

// ---------------- per-image: exact radix select + tie rule + sort + decode ----------------
__global__ void __launch_bounds__(1024) k_selsort(
    const unsigned long long* __restrict__ cand, const unsigned int* __restrict__ cnt,
    const float* __restrict__ anchors, const float* __restrict__ deltas,
    float* __restrict__ boxes, float* __restrict__ scores,
    float* __restrict__ areas, unsigned int* __restrict__ valid){
  __shared__ unsigned long long sel_l[SORT_N];  // 16 KB
  __shared__ unsigned int bins[2048];           // 8 KB
  __shared__ unsigned int scal[4];              // rem, bin, cgt, ceq
  int img = blockIdx.x, tid = threadIdx.x;
  unsigned int n = cnt[img*CNT_STRIDE]; if (n > CAND_CAP) n = CAND_CAP;
  const unsigned long long* cd = cand + (size_t)img*CAND_CAP;

  unsigned int rem = PRE_K, prefix = 0;
  #pragma unroll
  for (int p = 0; p < 3; ++p){
    int shift  = (p==0) ? 21 : (p==1) ? 10 : 0;
    int mshift = (p==0) ? 32 : (p==1) ? 21 : 10;
    unsigned int bmask = (p==2) ? 1023u : 2047u;
    bins[tid] = 0; bins[tid+1024] = 0;
    __syncthreads();
    for (unsigned int i = tid; i < n; i += 1024){
      unsigned int k32 = (unsigned int)(cd[i] >> 32);
      bool m = (mshift >= 32) || ((k32 >> mshift) == (prefix >> mshift));
      if (m) atomicAdd(&bins[(k32 >> shift) & bmask], 1u);
    }
    __syncthreads();
    // parallel suffix-sum over 2048 bins (Hillis-Steele)
    for (int off = 1; off < 2048; off <<= 1){
      unsigned int a0 = bins[tid]      + ((tid+off      < 2048) ? bins[tid+off]      : 0u);
      unsigned int a1 = bins[tid+1024] + ((tid+1024+off < 2048) ? bins[tid+1024+off] : 0u);
      __syncthreads();
      bins[tid] = a0; bins[tid+1024] = a1;
      __syncthreads();
    }
    // unique d with S[d] >= rem > S[d+1]
    #pragma unroll
    for (int h = 0; h < 2; ++h){
      int d = tid + h*1024;
      unsigned int Sd  = bins[d];
      unsigned int Sd1 = (d < 2047) ? bins[d+1] : 0u;
      if (Sd >= rem && Sd1 < rem){ scal[0] = rem - Sd1; scal[1] = (unsigned int)d; }
    }
    __syncthreads();
    rem = scal[0]; prefix |= scal[1] << shift;
    __syncthreads();
  }
  unsigned int T = prefix;
  unsigned int G = PRE_K - rem;   // # strictly greater than T; rem ties needed
  if (tid == 0){ scal[2] = 0; scal[3] = 0; }
  __syncthreads();
  for (unsigned int i = tid; i < n; i += 1024){
    unsigned long long pk = cd[i];
    unsigned int k32 = (unsigned int)(pk >> 32);
    if (k32 > T){
      unsigned int s = atomicAdd(&scal[2], 1u);   // s < G <= 1999
      sel_l[s] = pk;
    } else if (k32 == T){
      unsigned int e = atomicAdd(&scal[3], 1u);
      if (G + e < SORT_N) sel_l[G + e] = pk;      // ties; first rem after sort = smallest idx
    }
  }
  __syncthreads();
  unsigned int ceq = scal[3];
  unsigned int tcap = SORT_N - G;
  unsigned int filled = G + ((ceq < tcap) ? ceq : tcap);
  for (unsigned int i = filled + tid; i < SORT_N; i += 1024) sel_l[i] = 0ull;
  __syncthreads();
  // bitonic sort 2048 descending: (key desc, idx asc) via ~idx packing
  for (int k = 2; k <= SORT_N; k <<= 1){
    for (int j = k >> 1; j > 0; j >>= 1){
      for (int i = tid; i < SORT_N; i += 1024){
        int ixj = i ^ j;
        if (ixj > i){
          bool up = ((i & k) == 0);
          unsigned long long x = sel_l[i], y = sel_l[ixj];
          if ((x < y) == up){ sel_l[i] = y; sel_l[ixj] = x; }
        }
      }
      __syncthreads();
    }
  }
  // decode + clip the exact top-2000 (score rebuilt bit-exactly from key)
  for (int k = tid; k < PRE_K; k += 1024){
    unsigned long long pk = sel_l[k];
    unsigned int key = (unsigned int)(pk >> 32);
    unsigned int idx = ~(unsigned int)(pk & 0xFFFFFFFFull);
    unsigned int ub = (key & 0x80000000u) ? (key ^ 0x80000000u) : (key ^ 0xFFFFFFFFu);
    float sc = __uint_as_float(ub);
    float4 a = ((const float4*)anchors)[idx];
    float4 d = ((const float4*)deltas)[(size_t)img*N_ANCH + idx];
    float w  = rn_add(rn_sub(a.z, a.x), 1.0f);
    float h  = rn_add(rn_sub(a.w, a.y), 1.0f);
    float cx = rn_add(a.x, rn_mul(0.5f, w));
    float cy = rn_add(a.y, rn_mul(0.5f, h));
    float dw = fminf(d.z, DCLIP);
    float dh = fminf(d.w, DCLIP);
    float pcx = rn_add(rn_mul(d.x, w), cx);
    float pcy = rn_add(rn_mul(d.y, h), cy);
    float pw = rn_mul((float)exp((double)dw), w);   // correctly-rounded f32 exp
    float ph = rn_mul((float)exp((double)dh), h);
    float x1 = rn_sub(pcx, rn_mul(0.5f, pw));
    float y1 = rn_sub(pcy, rn_mul(0.5f, ph));
    float x2 = rn_sub(rn_add(pcx, rn_mul(0.5f, pw)), 1.0f);
    float y2 = rn_sub(rn_add(pcy, rn_mul(0.5f, ph)), 1.0f);
    x1 = fminf(fmaxf(x1, 0.0f), IMG_W_M1);
    x2 = fminf(fmaxf(x2, 0.0f), IMG_W_M1);
    y1 = fminf(fmaxf(y1, 0.0f), IMG_H_M1);
    y2 = fminf(fmaxf(y2, 0.0f), IMG_H_M1);
    float bw = rn_add(rn_sub(x2, x1), 1.0f);
    float bh = rn_add(rn_sub(y2, y1), 1.0f);
    ((float4*)boxes)[(size_t)img*PRE_K + k] = make_float4(x1, y1, x2, y2);
    scores[img*PRE_K + k] = sc;
    areas[img*PRE_K + k]  = rn_mul(bw, bh);
    valid[img*PRE_K + k]  = (bw >= 0.0f && bh >= 0.0f) ? 1u : 0u;
  }
}

// ---------------- NMS suppression bitmask, TRANSPOSED: mask_t[word][row] ----------------
// row-coalesced writes; rows [PRE_K, 2048) zeroed so downstream reads are safe.
__global__ void k_mask(const float* __restrict__ boxes, const float* __restrict__ areas,
                       unsigned long long* __restrict__ mask){
  int jblk = blockIdx.x, iblk = blockIdx.y, img = blockIdx.z;
  if (jblk < iblk) return;
  __shared__ float4 jb[64];
  __shared__ float  ja[64];
  int tj = jblk*64 + threadIdx.x;
  if (tj < PRE_K){
    jb[threadIdx.x] = ((const float4*)boxes)[(size_t)img*PRE_K + tj];
    ja[threadIdx.x] = areas[img*PRE_K + tj];
  }
  __syncthreads();
  int i = iblk*64 + threadIdx.x;
  unsigned long long bits = 0;
  if (i < PRE_K){
    float4 bi = ((const float4*)boxes)[(size_t)img*PRE_K + i];
    float ai = areas[img*PRE_K + i];
    int jmax = min(64, PRE_K - jblk*64);
    for (int b = 0; b < jmax; ++b){
      int j = jblk*64 + b;
      if (j <= i) continue;
      float4 bj = jb[b];
      if (iou_gt(bi.x,bi.y,bi.z,bi.w,ai, bj.x,bj.y,bj.z,bj.w,ja[b])) bits |= 1ull << b;
    }
  }
  mask[(size_t)img*(NMS_WORDS*MT_ROWS) + (size_t)jblk*MT_ROWS + i] = bits;
}

// ---------------- greedy NMS reduce: pair-resolve + distributed apply ----------------
// Round-8 evidence (58 us = ~4350 cyc/chunk): critical path = per-chunk
// shfl-reduce (~600) + readlane chain + vmcnt(0) wait forced by the cur=nxt
// register rotation (load issued ~100 cyc before use). This version:
//  - 16 barriers, not 32: wave p resolves BOTH its chunks (2p, 2p+1) in one
//    go; one butterfly reduces both halves; chunk 2p applied to word 2p+1
//    in-register via preloaded cross-diagonal block + 6-step OR-reduce.
//  - appliers consume loads issued one FULL iteration earlier (>=1200 cyc)
//    and re-issue right after consumption: vmcnt wait fully covered.
__global__ void __launch_bounds__(1024) k_nms_out(const unsigned long long* __restrict__ mask,
                          const unsigned int* __restrict__ valid,
                          const float* __restrict__ boxes, const float* __restrict__ scores,
                          float* __restrict__ out){
  __shared__ unsigned long long keepw[NMS_WORDS];
  __shared__ unsigned int kpre[NMS_WORDS + 1];
  int img = blockIdx.x;
  int tid = threadIdx.x;
  int wv = tid >> 6, lane = tid & 63;
  const unsigned long long* mt = mask + (size_t)img * (NMS_WORDS * MT_ROWS);

  // preload this wave's diagonal blocks + cross block + valid ballots
  int cA = wv*2, cB = wv*2 + 1;
  unsigned long long dgA = mt[(size_t)cA*MT_ROWS + cA*64 + lane];
  unsigned long long dgB = mt[(size_t)cB*MT_ROWS + cB*64 + lane];
  unsigned long long dgX = mt[(size_t)cB*MT_ROWS + cA*64 + lane]; // word cB, rows of chunk cA
  int rA = cA*64 + lane, rB = cB*64 + lane;
  bool okA = (rA < PRE_K) && (valid[img*PRE_K + rA] != 0u);
  bool okB = (rB < PRE_K) && (valid[img*PRE_K + rB] != 0u);
  unsigned long long vA = __ballot(okA);
  unsigned long long vB = __ballot(okB);

  // apply mapping: thread -> (word w, row-pair r2)
  int w  = wv*2 + (lane >> 5);
  int r2 = lane & 31;
  unsigned long long acc = 0;

  // prologue: issue loads for iteration 0 (appliers are waves wv >= 1)
  ulonglong2 c0, c1; c0.x = c0.y = c1.x = c1.y = 0;
  if (wv > 0){
    c0 = *(const ulonglong2*)(mt + (size_t)w*MT_ROWS + 0*64 + r2*2);
    c1 = *(const ulonglong2*)(mt + (size_t)w*MT_ROWS + 1*64 + r2*2);
  }

  for (int p = 0; p < NPAIR; ++p){
    if (wv == p){
      // one butterfly reduces BOTH halves (lanes 0-31: word cA, 32-63: word cB)
      unsigned long long part = acc;
      part |= shflx_u64(part, 1);
      part |= shflx_u64(part, 2);
      part |= shflx_u64(part, 4);
      part |= shflx_u64(part, 8);
      part |= shflx_u64(part, 16);
      unsigned long long supA = readlane64(part, 0);
      unsigned long long supB = readlane64(part, 32);
      unsigned long long kA = vA & ~supA;
      #pragma unroll
      for (int b = 0; b < 64; ++b){
        unsigned long long dgb = readlane64(dgA, b);
        unsigned long long m = ((kA >> b) & 1ull) ? ~0ull : 0ull;
        kA &= ~(m & dgb);
      }
      // in-register apply chunk cA -> word cB
      unsigned long long x = ((kA >> lane) & 1ull) ? dgX : 0ull;
      x |= shflx_u64(x, 1);
      x |= shflx_u64(x, 2);
      x |= shflx_u64(x, 4);
      x |= shflx_u64(x, 8);
      x |= shflx_u64(x, 16);
      x |= shflx_u64(x, 32);
      unsigned long long kB = vB & ~(supB | readlane64(x, 0));
      #pragma unroll
      for (int b = 0; b < 64; ++b){
        unsigned long long dgb = readlane64(dgB, b);
        unsigned long long m = ((kB >> b) & 1ull) ? ~0ull : 0ull;
        kB &= ~(m & dgb);
      }
      if (lane == 0){ keepw[cA] = kA; keepw[cB] = kB; }
    }
    __syncthreads();
    if (wv > p){
      unsigned long long kb0 = keepw[2*p], kb1 = keepw[2*p + 1];
      unsigned long long m00 = ((kb0 >> (r2*2))   & 1ull) ? ~0ull : 0ull;
      unsigned long long m01 = ((kb0 >> (r2*2+1)) & 1ull) ? ~0ull : 0ull;
      unsigned long long m10 = ((kb1 >> (r2*2))   & 1ull) ? ~0ull : 0ull;
      unsigned long long m11 = ((kb1 >> (r2*2+1)) & 1ull) ? ~0ull : 0ull;
      acc |= (c0.x & m00) | (c0.y & m01) | (c1.x & m10) | (c1.y & m11);
      if (wv > p + 1){  // re-issue for next iteration (consumed after next barrier)
        c0 = *(const ulonglong2*)(mt + (size_t)w*MT_ROWS + (size_t)(2*p+2)*64 + r2*2);
        c1 = *(const ulonglong2*)(mt + (size_t)w*MT_ROWS + (size_t)(2*p+3)*64 + r2*2);
      }
    }
  }

  // pack: keepw[] holds final keep words
  if (tid == 0){
    unsigned int s = 0;
    for (int ww = 0; ww < NMS_WORDS; ++ww){ kpre[ww] = s; s += __popcll(keepw[ww]); }
    kpre[NMS_WORDS] = s;
  }
  __syncthreads();
  unsigned int nkept = kpre[NMS_WORDS];
  for (int i = tid; i < PRE_K; i += blockDim.x){
    int ww = i >> 6, b = i & 63;
    unsigned long long kw = keepw[ww];
    bool kept = (kw >> b) & 1ull;
    unsigned long long below = (b == 0) ? 0ull : (kw & ((~0ull) >> (64 - b)));
    unsigned int rank = kpre[ww] + (unsigned int)__popcll(below);
    unsigned int pos = kept ? rank : (nkept + (unsigned int)i - rank);
    if (pos < POST_K){
      float4 bx = ((const float4*)boxes)[(size_t)img*PRE_K + i];
      float sc = kept ? scores[img*PRE_K + i] : -1e9f;
      float* o = out + ((size_t)img*POST_K + pos) * 5;
      o[0] = bx.x; o[1] = bx.y; o[2] = bx.z; o[3] = bx.w; o[4] = sc;
    }
  }
}

extern "C" void kernel_launch(void* const* d_in, const int* in_sizes, int n_in,
                              void* d_out, int out_size, void* d_ws, size_t ws_size,
                              hipStream_t stream) {
  const float* anchors    = (const float*)d_in[0];
  const float* objectness = (const float*)d_in[1];
  const float* deltas     = (const float*)d_in[2];
  float* out = (float*)d_out;
  char* ws = (char*)d_ws;

  unsigned int* hist       = (unsigned int*)(ws + 0);        // 65536
  unsigned int* state      = (unsigned int*)(ws + 65536);    // 32
  unsigned int* cnt        = (unsigned int*)(ws + 65600);    // 2048 (256B/img)
  float* boxes             = (float*)(ws + 67648);           // 256000 (16B aligned)
  float* scores            = (float*)(ws + 323648);          // 64000
  float* areas             = (float*)(ws + 387648);          // 64000
  unsigned int* valid      = (unsigned int*)(ws + 451648);   // 64000
  unsigned long long* mask = (unsigned long long*)(ws + 515648); // 4,194,304 (transposed, 2048 rows)
  // candidate buffer overlays mask region: fully consumed by k_selsort BEFORE
  // k_mask writes mask (in-order stream). 8*8192*8 = 512 KB <= 4 MB.
  unsigned long long* cand = (unsigned long long*)(ws + 515648);

  hipLaunchKernelGGL(k_init, dim3(32), dim3(256), 0, stream, hist, cnt);
  hipLaunchKernelGGL(k_hist, dim3(64, N_IMG), dim3(256), 0, stream, objectness, hist);
  hipLaunchKernelGGL(k_scan, dim3(N_IMG), dim3(64), 0, stream, hist, state);
  hipLaunchKernelGGL(k_cand, dim3(64, N_IMG), dim3(256), 0, stream,
                     objectness, state, cnt, cand);
  hipLaunchKernelGGL(k_selsort, dim3(N_IMG), dim3(1024), 0, stream,
                     cand, cnt, anchors, deltas, boxes, scores, areas, valid);
  hipLaunchKernelGGL(k_mask, dim3(NMS_WORDS, NMS_WORDS, N_IMG), dim3(64), 0, stream,
                     boxes, areas, mask);
  hipLaunchKernelGGL(k_nms_out, dim3(N_IMG), dim3(1024), 0, stream,
                     mask, valid, boxes, scores, out);
}